// Round 1
// baseline (1227.504 us; speedup 1.0000x reference)
//
#include <hip/hip_runtime.h>
#include <hip/hip_bf16.h>

// GCN layer, restructured:
//   A1[n] = sum_{e: dst=n} norm_e * x[src_e]           (x = concat(srcEmb, dstEmb))
//   A2[n] = sum_{e: dst=n} norm_e * (x[src_e]*x[dst_e])
//   c[n]  = sum_{e: dst=n} norm_e
//   out[n] = LeakyReLU( A1[n] @ W1^T + A2[n] @ W2^T + c[n]*(b1+b2), 0.2 )
//
// A1 lives in d_out (overwritten in-place by the final kernel).
// A2 and c live in d_ws.

#define LANES 64

__global__ __launch_bounds__(256) void edge_scatter_kernel(
    const float* __restrict__ srcEmb, const float* __restrict__ dstEmb,
    const float* __restrict__ norm,
    const int* __restrict__ es, const int* __restrict__ ed,
    float* __restrict__ A1, float* __restrict__ A2, float* __restrict__ cnt,
    int E, int n_src)
{
    int idx  = blockIdx.x * blockDim.x + threadIdx.x;
    int e    = idx >> 6;          // one wave (64 lanes) per edge
    int lane = idx & 63;          // lane = feature index
    if (e >= E) return;

    int s = es[e];
    int d = ed[e];
    float w = norm[e];

    const float* xs_row = (s < n_src) ? (srcEmb + (size_t)s * 64)
                                      : (dstEmb + (size_t)(s - n_src) * 64);
    const float* xd_row = (d < n_src) ? (srcEmb + (size_t)d * 64)
                                      : (dstEmb + (size_t)(d - n_src) * 64);

    float xs = xs_row[lane];
    float xd = xd_row[lane];

    atomicAdd(&A1[(size_t)d * 64 + lane], w * xs);
    atomicAdd(&A2[(size_t)d * 64 + lane], w * xs * xd);
    if (lane == 0) atomicAdd(&cnt[d], w);
}

// Per-node dual mat-vec: out[n,o] = LeakyReLU( sum_d A1[n,d]*W1[o,d]
//                                            + sum_d A2[n,d]*W2[o,d]
//                                            + c[n]*(b1[o]+b2[o]) )
// 256 threads = 4 rows/block, thread -> (r = t>>6, o = t&63).
__global__ __launch_bounds__(256) void node_gemm_kernel(
    const float* __restrict__ A1, const float* __restrict__ A2,
    const float* __restrict__ cnt,
    const float* __restrict__ W1, const float* __restrict__ b1,
    const float* __restrict__ W2, const float* __restrict__ b2,
    float* __restrict__ out, int Ntot)
{
    __shared__ float w1t[64 * 64];   // w1t[d*64+o] = W1[o*64+d]
    __shared__ float w2t[64 * 64];
    __shared__ float rA1[4][64];
    __shared__ float rA2[4][64];

    int t = threadIdx.x;
    // Transpose weights into LDS (one-time per block).
    for (int i = t; i < 64 * 64; i += 256) {
        int o = i >> 6;      // row of W (output feature)
        int d = i & 63;      // col of W (input feature)
        w1t[d * 64 + o] = W1[i];
        w2t[d * 64 + o] = W2[i];
    }

    int r   = t >> 6;
    int o   = t & 63;
    int row = blockIdx.x * 4 + r;

    float a1 = 0.f, a2 = 0.f, cn = 0.f;
    if (row < Ntot) {
        rA1[r][o] = A1[(size_t)row * 64 + o];
        rA2[r][o] = A2[(size_t)row * 64 + o];
        cn = cnt[row];
    }
    __syncthreads();

    if (row >= Ntot) return;

    float acc = cn * (b1[o] + b2[o]);
    #pragma unroll 8
    for (int d = 0; d < 64; ++d) {
        acc += rA1[r][d] * w1t[d * 64 + o];
        acc += rA2[r][d] * w2t[d * 64 + o];
    }
    out[(size_t)row * 64 + o] = (acc > 0.f) ? acc : 0.2f * acc;
}

extern "C" void kernel_launch(void* const* d_in, const int* in_sizes, int n_in,
                              void* d_out, int out_size, void* d_ws, size_t ws_size,
                              hipStream_t stream) {
    const float* srcEmb = (const float*)d_in[0];
    const float* dstEmb = (const float*)d_in[1];
    const float* norm   = (const float*)d_in[2];
    const float* W1     = (const float*)d_in[3];
    const float* b1     = (const float*)d_in[4];
    const float* W2     = (const float*)d_in[5];
    const float* b2     = (const float*)d_in[6];
    const int*   es     = (const int*)d_in[7];
    const int*   ed     = (const int*)d_in[8];

    const int n_src = in_sizes[0] / 64;
    const int n_dst = in_sizes[1] / 64;
    const int Ntot  = n_src + n_dst;
    const int E     = in_sizes[7];

    float* A1  = (float*)d_out;                       // N*64
    float* A2  = (float*)d_ws;                        // N*64
    float* cnt = (float*)d_ws + (size_t)Ntot * 64;    // N

    // Zero accumulators (d_out / d_ws are poisoned 0xAA before every call).
    hipMemsetAsync(d_out, 0, (size_t)out_size * sizeof(float), stream);
    hipMemsetAsync(d_ws, 0, ((size_t)Ntot * 64 + Ntot) * sizeof(float), stream);

    // Edge scatter: one 64-lane wave per edge, 4 edges per 256-thread block.
    {
        long long total = (long long)E * 64;
        int blocks = (int)((total + 255) / 256);
        edge_scatter_kernel<<<blocks, 256, 0, stream>>>(
            srcEmb, dstEmb, norm, es, ed, A1, A2, cnt, E, n_src);
    }

    // Node-level dual mat-vec + bias + LeakyReLU (in-place on d_out).
    {
        int blocks = (Ntot + 3) / 4;
        node_gemm_kernel<<<blocks, 256, 0, stream>>>(
            A1, A2, cnt, W1, b1, W2, b2, (float*)d_out, Ntot);
    }
}

// Round 2
// 512.798 us; speedup vs baseline: 2.3937x; 2.3937x over previous
//
#include <hip/hip_runtime.h>
#include <hip/hip_bf16.h>

// GCN layer, restructured + edges counting-sorted by destination (no atomics
// on the feature accumulators):
//   1. histogram deg[d], exclusive scan -> offsets, scatter (src,norm) sorted by dst
//   2. one wave per node: A1[n] = sum w*x[src], A2[n] = sum w*(x[src]*x[n]), c[n]=sum w
//   3. out[n] = LeakyReLU(A1 @ W1^T + A2 @ W2^T + c*(b1+b2), 0.2)
//
// ws layout (4-byte units): A2[N*64] | cnt[N] | offsets[N+1] | cursors[N] |
//                           partials[256] | sorted_src[E] | sorted_norm[E]

__device__ __forceinline__ const float* row_ptr(int idx, const float* srcEmb,
                                                const float* dstEmb, int n_src) {
    return (idx < n_src) ? (srcEmb + (size_t)idx * 64)
                         : (dstEmb + (size_t)(idx - n_src) * 64);
}

__global__ __launch_bounds__(256) void hist_kernel(
    const int* __restrict__ ed, int* __restrict__ counts, int E)
{
    int e = blockIdx.x * 256 + threadIdx.x;
    if (e < E) atomicAdd(&counts[ed[e]], 1);
}

// Block-level exclusive scan: 1024 elements/block, 256 threads, 4 consecutive
// elements per thread. Writes exclusive prefix (block-local) in place, block
// total to partials[blockIdx.x].
__global__ __launch_bounds__(256) void scan1_kernel(
    int* __restrict__ data, int* __restrict__ partials, int n)
{
    __shared__ int sc[256];
    int t = threadIdx.x;
    int base = blockIdx.x * 1024 + t * 4;
    int v[4];
    #pragma unroll
    for (int k = 0; k < 4; ++k) v[k] = (base + k < n) ? data[base + k] : 0;
    int sum = v[0] + v[1] + v[2] + v[3];
    sc[t] = sum;
    __syncthreads();
    for (int off = 1; off < 256; off <<= 1) {
        int x = 0;
        if (t >= off) x = sc[t - off];
        __syncthreads();
        if (t >= off) sc[t] += x;
        __syncthreads();
    }
    int ex = sc[t] - sum;    // exclusive prefix of this thread's chunk
    #pragma unroll
    for (int k = 0; k < 4; ++k) {
        if (base + k < n) data[base + k] = ex;
        ex += v[k];
    }
    if (t == 255) partials[blockIdx.x] = sc[255];
}

// Exclusive scan of <=256 partials, single block.
__global__ __launch_bounds__(256) void scan2_kernel(
    int* __restrict__ partials, int nblocks)
{
    __shared__ int sc[256];
    int t = threadIdx.x;
    int v = (t < nblocks) ? partials[t] : 0;
    sc[t] = v;
    __syncthreads();
    for (int off = 1; off < 256; off <<= 1) {
        int x = 0;
        if (t >= off) x = sc[t - off];
        __syncthreads();
        if (t >= off) sc[t] += x;
        __syncthreads();
    }
    partials[t] = sc[t] - v;
}

__global__ __launch_bounds__(256) void add_offsets_kernel(
    int* __restrict__ offsets, const int* __restrict__ partials,
    int* __restrict__ cursors, int n, int E)
{
    int i = blockIdx.x * 256 + threadIdx.x;
    if (i < n) {
        int v = offsets[i] + partials[i >> 10];
        offsets[i] = v;
        cursors[i] = v;
    }
    if (i == 0) offsets[n] = E;
}

__global__ __launch_bounds__(256) void scatter_kernel(
    const int* __restrict__ es, const int* __restrict__ ed,
    const float* __restrict__ norm, int* __restrict__ cursors,
    int* __restrict__ ssrc, float* __restrict__ snorm, int E)
{
    int e = blockIdx.x * 256 + threadIdx.x;
    if (e >= E) return;
    int d = ed[e];
    int pos = atomicAdd(&cursors[d], 1);
    ssrc[pos]  = es[e];
    snorm[pos] = norm[e];
}

// One wave (64 lanes) per node, lane = feature. Accumulate the node's edge
// segment in registers, write A1/A2/cnt once. No atomics.
__global__ __launch_bounds__(256) void accumulate_kernel(
    const float* __restrict__ srcEmb, const float* __restrict__ dstEmb,
    const int* __restrict__ offsets,
    const int* __restrict__ ssrc, const float* __restrict__ snorm,
    float* __restrict__ A1, float* __restrict__ A2, float* __restrict__ cnt,
    int Ntot, int n_src)
{
    int idx  = blockIdx.x * 256 + threadIdx.x;
    int n    = idx >> 6;
    int lane = idx & 63;
    if (n >= Ntot) return;

    int off0 = offsets[n];
    int off1 = offsets[n + 1];

    float xd = row_ptr(n, srcEmb, dstEmb, n_src)[lane];

    float a1 = 0.f, a2 = 0.f, c = 0.f;
    int j = off0;
    for (; j + 1 < off1; j += 2) {
        int   s0 = ssrc[j],     s1 = ssrc[j + 1];
        float w0 = snorm[j],    w1 = snorm[j + 1];
        float x0 = row_ptr(s0, srcEmb, dstEmb, n_src)[lane];
        float x1 = row_ptr(s1, srcEmb, dstEmb, n_src)[lane];
        a1 += w0 * x0 + w1 * x1;
        a2 += (w0 * x0) * xd + (w1 * x1) * xd;
        c  += w0 + w1;
    }
    if (j < off1) {
        int   s0 = ssrc[j];
        float w0 = snorm[j];
        float x0 = row_ptr(s0, srcEmb, dstEmb, n_src)[lane];
        a1 += w0 * x0;
        a2 += (w0 * x0) * xd;
        c  += w0;
    }

    A1[(size_t)n * 64 + lane] = a1;
    A2[(size_t)n * 64 + lane] = a2;
    if (lane == 0) cnt[n] = c;
}

// 16 rows per block: amortize the 32 KB W1/W2 staging 4x over round 1, and
// reuse each LDS w-read across 4 row-accumulators.
__global__ __launch_bounds__(256) void node_gemm_kernel(
    const float* __restrict__ A1, const float* __restrict__ A2,
    const float* __restrict__ cnt,
    const float* __restrict__ W1, const float* __restrict__ b1,
    const float* __restrict__ W2, const float* __restrict__ b2,
    float* __restrict__ out, int Ntot)
{
    __shared__ float w1t[64 * 64];   // w1t[d*64+o] = W1[o*64+d]
    __shared__ float w2t[64 * 64];
    __shared__ float sA1[16][64];
    __shared__ float sA2[16][64];
    __shared__ float scn[16];

    int t = threadIdx.x;
    for (int i = t; i < 64 * 64; i += 256) {
        int o = i >> 6, d = i & 63;
        w1t[d * 64 + o] = W1[i];
        w2t[d * 64 + o] = W2[i];
    }
    int base = blockIdx.x * 16;
    for (int i = t; i < 16 * 64; i += 256) {
        int r = i >> 6, c = i & 63;
        int row = base + r;
        float v1 = 0.f, v2 = 0.f;
        if (row < Ntot) {
            v1 = A1[(size_t)row * 64 + c];
            v2 = A2[(size_t)row * 64 + c];
        }
        sA1[r][c] = v1;
        sA2[r][c] = v2;
    }
    if (t < 16) scn[t] = (base + t < Ntot) ? cnt[base + t] : 0.f;
    __syncthreads();

    int o  = t & 63;
    int r0 = t >> 6;                 // rows r0, r0+4, r0+8, r0+12
    float bsum = b1[o] + b2[o];
    float acc0 = scn[r0]      * bsum;
    float acc1 = scn[r0 + 4]  * bsum;
    float acc2 = scn[r0 + 8]  * bsum;
    float acc3 = scn[r0 + 12] * bsum;

    #pragma unroll 4
    for (int d = 0; d < 64; ++d) {
        float w1 = w1t[d * 64 + o];
        float w2 = w2t[d * 64 + o];
        acc0 += sA1[r0][d]      * w1 + sA2[r0][d]      * w2;
        acc1 += sA1[r0 + 4][d]  * w1 + sA2[r0 + 4][d]  * w2;
        acc2 += sA1[r0 + 8][d]  * w1 + sA2[r0 + 8][d]  * w2;
        acc3 += sA1[r0 + 12][d] * w1 + sA2[r0 + 12][d] * w2;
    }

    #pragma unroll
    for (int k = 0; k < 4; ++k) {
        int row = base + r0 + 4 * k;
        if (row < Ntot) {
            float a = (k == 0) ? acc0 : (k == 1) ? acc1 : (k == 2) ? acc2 : acc3;
            out[(size_t)row * 64 + o] = (a > 0.f) ? a : 0.2f * a;
        }
    }
}

extern "C" void kernel_launch(void* const* d_in, const int* in_sizes, int n_in,
                              void* d_out, int out_size, void* d_ws, size_t ws_size,
                              hipStream_t stream) {
    const float* srcEmb = (const float*)d_in[0];
    const float* dstEmb = (const float*)d_in[1];
    const float* norm   = (const float*)d_in[2];
    const float* W1     = (const float*)d_in[3];
    const float* b1     = (const float*)d_in[4];
    const float* W2     = (const float*)d_in[5];
    const float* b2     = (const float*)d_in[6];
    const int*   es     = (const int*)d_in[7];
    const int*   ed     = (const int*)d_in[8];

    const int n_src = in_sizes[0] / 64;
    const int n_dst = in_sizes[1] / 64;
    const int Ntot  = n_src + n_dst;
    const int E     = in_sizes[7];

    // Workspace carve-up (all 4-byte elements).
    float* A2       = (float*)d_ws;                  // Ntot*64
    float* cnt      = A2 + (size_t)Ntot * 64;        // Ntot
    int*   offsets  = (int*)(cnt + Ntot);            // Ntot+1
    int*   cursors  = offsets + Ntot + 1;            // Ntot
    int*   partials = cursors + Ntot;                // 256
    int*   ssrc     = partials + 256;                // E
    float* snorm    = (float*)(ssrc + E);            // E
    float* A1       = (float*)d_out;                 // Ntot*64 (in-place)

    const int scan_blocks = (Ntot + 1023) / 1024;

    // 1. zero degree counts (in the offsets array)
    hipMemsetAsync(offsets, 0, (size_t)Ntot * sizeof(int), stream);

    // 2. histogram of edge destinations
    hist_kernel<<<(E + 255) / 256, 256, 0, stream>>>(ed, offsets, E);

    // 3. exclusive scan -> offsets, cursors
    scan1_kernel<<<scan_blocks, 256, 0, stream>>>(offsets, partials, Ntot);
    scan2_kernel<<<1, 256, 0, stream>>>(partials, scan_blocks);
    add_offsets_kernel<<<(Ntot + 255) / 256, 256, 0, stream>>>(
        offsets, partials, cursors, Ntot, E);

    // 4. scatter edges into dst-sorted order
    scatter_kernel<<<(E + 255) / 256, 256, 0, stream>>>(
        es, ed, norm, cursors, ssrc, snorm, E);

    // 5. per-node accumulation (no atomics)
    accumulate_kernel<<<(Ntot + 3) / 4, 256, 0, stream>>>(
        srcEmb, dstEmb, offsets, ssrc, snorm, A1, A2, cnt, Ntot, n_src);

    // 6. node-level dual mat-vec + bias + LeakyReLU (in-place on d_out)
    node_gemm_kernel<<<(Ntot + 15) / 16, 256, 0, stream>>>(
        A1, A2, cnt, W1, b1, W2, b2, (float*)d_out, Ntot);
}

// Round 3
// 440.242 us; speedup vs baseline: 2.7882x; 1.1648x over previous
//
#include <hip/hip_runtime.h>
#include <hip/hip_bf16.h>

// GCN layer, restructured + edges counting-sorted by destination:
//   1. histogram deg[d], exclusive scan -> offsets, scatter packed (src,norm)
//   2. one wave per node: A1[n] = sum w*x[src], A2[n] = sum w*(x[src]*x[n]), c[n]=sum w
//   3. out[n] = LeakyReLU(A1 @ W1^T + A2 @ W2^T + c*(b1+b2), 0.2)
//
// ws layout (4-byte units): A2[N*64] | cnt[N] | offsets[N+1] | cursors[N] |
//                           partials[256] | (align 8B) | epack[E] (int2)

__device__ __forceinline__ const float* row_ptr(int idx, const float* srcEmb,
                                                const float* dstEmb, int n_src) {
    return (idx < n_src) ? (srcEmb + (size_t)idx * 64)
                         : (dstEmb + (size_t)(idx - n_src) * 64);
}

__global__ __launch_bounds__(256) void hist_kernel(
    const int* __restrict__ ed, int* __restrict__ counts, int E)
{
    int e = blockIdx.x * 256 + threadIdx.x;
    if (e < E) atomicAdd(&counts[ed[e]], 1);
}

__global__ __launch_bounds__(256) void scan1_kernel(
    int* __restrict__ data, int* __restrict__ partials, int n)
{
    __shared__ int sc[256];
    int t = threadIdx.x;
    int base = blockIdx.x * 1024 + t * 4;
    int v[4];
    #pragma unroll
    for (int k = 0; k < 4; ++k) v[k] = (base + k < n) ? data[base + k] : 0;
    int sum = v[0] + v[1] + v[2] + v[3];
    sc[t] = sum;
    __syncthreads();
    for (int off = 1; off < 256; off <<= 1) {
        int x = 0;
        if (t >= off) x = sc[t - off];
        __syncthreads();
        if (t >= off) sc[t] += x;
        __syncthreads();
    }
    int ex = sc[t] - sum;
    #pragma unroll
    for (int k = 0; k < 4; ++k) {
        if (base + k < n) data[base + k] = ex;
        ex += v[k];
    }
    if (t == 255) partials[blockIdx.x] = sc[255];
}

__global__ __launch_bounds__(256) void scan2_kernel(
    int* __restrict__ partials, int nblocks)
{
    __shared__ int sc[256];
    int t = threadIdx.x;
    int v = (t < nblocks) ? partials[t] : 0;
    sc[t] = v;
    __syncthreads();
    for (int off = 1; off < 256; off <<= 1) {
        int x = 0;
        if (t >= off) x = sc[t - off];
        __syncthreads();
        if (t >= off) sc[t] += x;
        __syncthreads();
    }
    partials[t] = sc[t] - v;
}

__global__ __launch_bounds__(256) void add_offsets_kernel(
    int* __restrict__ offsets, const int* __restrict__ partials,
    int* __restrict__ cursors, int n, int E)
{
    int i = blockIdx.x * 256 + threadIdx.x;
    if (i < n) {
        int v = offsets[i] + partials[i >> 10];
        offsets[i] = v;
        cursors[i] = v;
    }
    if (i == 0) offsets[n] = E;
}

__global__ __launch_bounds__(256) void scatter_kernel(
    const int* __restrict__ es, const int* __restrict__ ed,
    const float* __restrict__ norm, int* __restrict__ cursors,
    int2* __restrict__ epack, int E)
{
    int e = blockIdx.x * 256 + threadIdx.x;
    if (e >= E) return;
    int d = ed[e];
    int pos = atomicAdd(&cursors[d], 1);
    epack[pos] = make_int2(es[e], __float_as_int(norm[e]));
}

// One wave per node, lane = feature. Load up to 64 packed edges with ONE
// coalesced int2 load, then broadcast each edge via __shfl (readlane) --
// no dependent per-edge scalar global loads.
__global__ __launch_bounds__(256) void accumulate_kernel(
    const float* __restrict__ srcEmb, const float* __restrict__ dstEmb,
    const int* __restrict__ offsets, const int2* __restrict__ epack,
    float* __restrict__ A1, float* __restrict__ A2, float* __restrict__ cnt,
    int Ntot, int n_src)
{
    int idx  = blockIdx.x * 256 + threadIdx.x;
    int n    = idx >> 6;
    int lane = idx & 63;
    if (n >= Ntot) return;

    int off0 = offsets[n];
    int off1 = offsets[n + 1];

    float xd = row_ptr(n, srcEmb, dstEmb, n_src)[lane];

    float a1 = 0.f, a2 = 0.f, c = 0.f;
    for (int base = off0; base < off1; base += 64) {
        int m = off1 - base; if (m > 64) m = 64;
        int sp = 0; float wp = 0.f;
        if (lane < m) {
            int2 pk = epack[base + lane];
            sp = pk.x;
            wp = __int_as_float(pk.y);
        }
        for (int k = 0; k < m; ++k) {
            int   s = __shfl(sp, k);
            float w = __shfl(wp, k);
            float x = row_ptr(s, srcEmb, dstEmb, n_src)[lane];
            float wx = w * x;
            a1 += wx;
            a2 += wx * xd;
            c  += w;
        }
    }

    A1[(size_t)n * 64 + lane] = a1;
    A2[(size_t)n * 64 + lane] = a2;
    if (lane == 0) cnt[n] = c;
}

// 32 rows/block. W transposed into LDS with stride-65 padding (conflict-free
// both on the transposing write and the stride-1 read). A rows staged as
// float4 and read back as wave-uniform b128 broadcasts.
__global__ __launch_bounds__(256) void node_gemm_kernel(
    const float* __restrict__ A1, const float* __restrict__ A2,
    const float* __restrict__ cnt,
    const float* __restrict__ W1, const float* __restrict__ b1,
    const float* __restrict__ W2, const float* __restrict__ b2,
    float* __restrict__ out, int Ntot)
{
    __shared__ float  w1t[64 * 65];   // w1t[d*65+o] = W1[o*64+d]
    __shared__ float  w2t[64 * 65];
    __shared__ float4 sA1v[32][16];   // sA1v[r][q] = A1[base+r][4q..4q+3]
    __shared__ float4 sA2v[32][16];
    __shared__ float  scn[32];

    int t = threadIdx.x;
    for (int i = t; i < 64 * 64; i += 256) {
        int o = i >> 6, d = i & 63;
        w1t[d * 65 + o] = W1[i];
        w2t[d * 65 + o] = W2[i];
    }
    int base = blockIdx.x * 32;
    const float4* A1v = (const float4*)A1;
    const float4* A2v = (const float4*)A2;
    for (int i = t; i < 32 * 16; i += 256) {
        int r = i >> 4, q = i & 15;
        int row = base + r;
        float4 z; z.x = z.y = z.z = z.w = 0.f;
        sA1v[r][q] = (row < Ntot) ? A1v[(size_t)row * 16 + q] : z;
        sA2v[r][q] = (row < Ntot) ? A2v[(size_t)row * 16 + q] : z;
    }
    if (t < 32) scn[t] = (base + t < Ntot) ? cnt[base + t] : 0.f;
    __syncthreads();

    int o  = t & 63;
    int r0 = t >> 6;                  // rows r0 + 4k, k = 0..7
    float bsum = b1[o] + b2[o];
    float acc[8];
    #pragma unroll
    for (int k = 0; k < 8; ++k) acc[k] = scn[r0 + 4 * k] * bsum;

    for (int q = 0; q < 16; ++q) {
        float w10 = w1t[(4 * q + 0) * 65 + o];
        float w11 = w1t[(4 * q + 1) * 65 + o];
        float w12 = w1t[(4 * q + 2) * 65 + o];
        float w13 = w1t[(4 * q + 3) * 65 + o];
        float w20 = w2t[(4 * q + 0) * 65 + o];
        float w21 = w2t[(4 * q + 1) * 65 + o];
        float w22 = w2t[(4 * q + 2) * 65 + o];
        float w23 = w2t[(4 * q + 3) * 65 + o];
        #pragma unroll
        for (int k = 0; k < 8; ++k) {
            float4 a1 = sA1v[r0 + 4 * k][q];
            float4 a2 = sA2v[r0 + 4 * k][q];
            acc[k] += a1.x * w10 + a1.y * w11 + a1.z * w12 + a1.w * w13
                    + a2.x * w20 + a2.y * w21 + a2.z * w22 + a2.w * w23;
        }
    }

    #pragma unroll
    for (int k = 0; k < 8; ++k) {
        int row = base + r0 + 4 * k;
        if (row < Ntot) {
            float a = acc[k];
            out[(size_t)row * 64 + o] = (a > 0.f) ? a : 0.2f * a;
        }
    }
}

extern "C" void kernel_launch(void* const* d_in, const int* in_sizes, int n_in,
                              void* d_out, int out_size, void* d_ws, size_t ws_size,
                              hipStream_t stream) {
    const float* srcEmb = (const float*)d_in[0];
    const float* dstEmb = (const float*)d_in[1];
    const float* norm   = (const float*)d_in[2];
    const float* W1     = (const float*)d_in[3];
    const float* b1     = (const float*)d_in[4];
    const float* W2     = (const float*)d_in[5];
    const float* b2     = (const float*)d_in[6];
    const int*   es     = (const int*)d_in[7];
    const int*   ed     = (const int*)d_in[8];

    const int n_src = in_sizes[0] / 64;
    const int n_dst = in_sizes[1] / 64;
    const int Ntot  = n_src + n_dst;
    const int E     = in_sizes[7];

    // Workspace carve-up (4-byte units), epack 8B-aligned.
    float* A2       = (float*)d_ws;                  // Ntot*64
    float* cnt      = A2 + (size_t)Ntot * 64;        // Ntot
    int*   offsets  = (int*)(cnt + Ntot);            // Ntot+1
    int*   cursors  = offsets + Ntot + 1;            // Ntot
    int*   partials = cursors + Ntot;                // 256
    size_t off4     = (size_t)Ntot * 64 + Ntot + (Ntot + 1) + Ntot + 256;
    off4 = (off4 + 1) & ~(size_t)1;                  // 8B align
    int2*  epack    = (int2*)((float*)d_ws + off4);  // E int2
    float* A1       = (float*)d_out;                 // Ntot*64 (in-place)

    const int scan_blocks = (Ntot + 1023) / 1024;

    hipMemsetAsync(offsets, 0, (size_t)Ntot * sizeof(int), stream);

    hist_kernel<<<(E + 255) / 256, 256, 0, stream>>>(ed, offsets, E);

    scan1_kernel<<<scan_blocks, 256, 0, stream>>>(offsets, partials, Ntot);
    scan2_kernel<<<1, 256, 0, stream>>>(partials, scan_blocks);
    add_offsets_kernel<<<(Ntot + 255) / 256, 256, 0, stream>>>(
        offsets, partials, cursors, Ntot, E);

    scatter_kernel<<<(E + 255) / 256, 256, 0, stream>>>(
        es, ed, norm, cursors, epack, E);

    accumulate_kernel<<<(Ntot + 3) / 4, 256, 0, stream>>>(
        srcEmb, dstEmb, offsets, epack, A1, A2, cnt, Ntot, n_src);

    node_gemm_kernel<<<(Ntot + 31) / 32, 256, 0, stream>>>(
        A1, A2, cnt, W1, b1, W2, b2, (float*)d_out, Ntot);
}

// Round 4
// 410.914 us; speedup vs baseline: 2.9872x; 1.0714x over previous
//
#include <hip/hip_runtime.h>
#include <hip/hip_bf16.h>

// GCN layer. Key algebra: for fixed dst n, xd is segment-constant, so
//   A2[n] = sum norm*(xs.*xd) = (sum norm*xs) .* x[n] = A1[n] .* x[n]
// => only A1[n] and c[n] = sum norm are accumulated over edges.
//   out[n] = LeakyReLU(A1@W1^T + (A1.*x[n])@W2^T + c*(b1+b2), 0.2)
//
// Pipeline: bf16 table prep | hist | scan | scatter packed(src,norm->4B) |
//           per-node segment accumulate (bf16 gathers, 2 edges/wave-iter) |
//           fused node GEMM.
//
// ws (4B units): cnt[N] | offsets[N+1] | cursors[N] | partials[256] |
//                epk[E] | xbf[N*32] (bf16x2 words)

__device__ __forceinline__ unsigned short f2bf(float f) {
    unsigned int u = __float_as_uint(f);
    u += 0x7fffu + ((u >> 16) & 1u);      // round-to-nearest-even
    return (unsigned short)(u >> 16);
}

// Build concatenated bf16 node table: xbf[n*32+f] packs features {2f,2f+1}.
__global__ __launch_bounds__(256) void prep_bf16_kernel(
    const float* __restrict__ srcEmb, const float* __restrict__ dstEmb,
    unsigned int* __restrict__ xbf, int Ntot, int n_src)
{
    int i = blockIdx.x * 256 + threadIdx.x;      // pair index
    if (i >= Ntot * 32) return;
    int n = i >> 5, f = i & 31;
    const float* row = (n < n_src) ? srcEmb + (size_t)n * 64
                                   : dstEmb + (size_t)(n - n_src) * 64;
    float2 v = ((const float2*)row)[f];
    xbf[i] = ((unsigned int)f2bf(v.y) << 16) | f2bf(v.x);
}

__global__ __launch_bounds__(256) void hist_kernel(
    const int* __restrict__ ed, int* __restrict__ counts, int E)
{
    int e = (blockIdx.x * 256 + threadIdx.x) << 2;
    if (e + 3 < E) {
        int4 v = *(const int4*)(ed + e);
        atomicAdd(&counts[v.x], 1);
        atomicAdd(&counts[v.y], 1);
        atomicAdd(&counts[v.z], 1);
        atomicAdd(&counts[v.w], 1);
    } else {
        for (int j = e; j < E; ++j) atomicAdd(&counts[ed[j]], 1);
    }
}

__global__ __launch_bounds__(256) void scan1_kernel(
    int* __restrict__ data, int* __restrict__ partials, int n)
{
    __shared__ int sc[256];
    int t = threadIdx.x;
    int base = blockIdx.x * 1024 + t * 4;
    int v[4];
    #pragma unroll
    for (int k = 0; k < 4; ++k) v[k] = (base + k < n) ? data[base + k] : 0;
    int sum = v[0] + v[1] + v[2] + v[3];
    sc[t] = sum;
    __syncthreads();
    for (int off = 1; off < 256; off <<= 1) {
        int x = 0;
        if (t >= off) x = sc[t - off];
        __syncthreads();
        if (t >= off) sc[t] += x;
        __syncthreads();
    }
    int ex = sc[t] - sum;
    #pragma unroll
    for (int k = 0; k < 4; ++k) {
        if (base + k < n) data[base + k] = ex;
        ex += v[k];
    }
    if (t == 255) partials[blockIdx.x] = sc[255];
}

__global__ __launch_bounds__(256) void scan2_kernel(
    int* __restrict__ partials, int nblocks)
{
    __shared__ int sc[256];
    int t = threadIdx.x;
    int v = (t < nblocks) ? partials[t] : 0;
    sc[t] = v;
    __syncthreads();
    for (int off = 1; off < 256; off <<= 1) {
        int x = 0;
        if (t >= off) x = sc[t - off];
        __syncthreads();
        if (t >= off) sc[t] += x;
        __syncthreads();
    }
    partials[t] = sc[t] - v;
}

__global__ __launch_bounds__(256) void add_offsets_kernel(
    int* __restrict__ offsets, const int* __restrict__ partials,
    int* __restrict__ cursors, int n, int E)
{
    int i = blockIdx.x * 256 + threadIdx.x;
    if (i < n) {
        int v = offsets[i] + partials[i >> 10];
        offsets[i] = v;
        cursors[i] = v;
    }
    if (i == 0) offsets[n] = E;
}

// Scatter packed word: (src << 15) | round(norm * 32767). 4 B per edge halves
// the write-amplified random-store traffic vs an 8 B (src,norm) pair.
__global__ __launch_bounds__(256) void scatter_kernel(
    const int* __restrict__ es, const int* __restrict__ ed,
    const float* __restrict__ norm, int* __restrict__ cursors,
    unsigned int* __restrict__ epk, int E)
{
    int e = blockIdx.x * 256 + threadIdx.x;
    if (e >= E) return;
    int d = ed[e];
    int pos = atomicAdd(&cursors[d], 1);
    unsigned int q = (unsigned int)(norm[e] * 32767.f + 0.5f);
    if (q > 32767u) q = 32767u;
    epk[pos] = ((unsigned int)es[e] << 15) | q;
}

// One wave per node. Half-wave per edge (lane = (h, sl): h=edge parity,
// sl = feature pair). 64 packed edges loaded coalesced, broadcast by
// bpermute; bf16x2 gathers (128 B/row). Only a1 (float2/lane) + c.
__global__ __launch_bounds__(256) void accumulate_kernel(
    const unsigned int* __restrict__ xbf,
    const int* __restrict__ offsets, const unsigned int* __restrict__ epk,
    float* __restrict__ A1, float* __restrict__ cnt, int Ntot)
{
    int idx  = blockIdx.x * 256 + threadIdx.x;
    int n    = idx >> 6;
    int lane = idx & 63;
    if (n >= Ntot) return;
    int sl = lane & 31;
    int h  = lane >> 5;

    int off0 = offsets[n];
    int off1 = offsets[n + 1];

    float a1x = 0.f, a1y = 0.f, c = 0.f;
    for (int base = off0; base < off1; base += 64) {
        int m = off1 - base; if (m > 64) m = 64;
        unsigned int pw = (lane < m) ? epk[base + lane] : 0u;  // 0 => w=0,s=0
        for (int k2 = 0; k2 < m; k2 += 2) {
            unsigned int pk = __shfl(pw, k2 + h);
            float w = (float)(pk & 0x7fffu) * (1.f / 32767.f);
            unsigned int s = pk >> 15;
            unsigned int u = xbf[s * 32 + sl];
            float x0 = __uint_as_float(u << 16);
            float x1 = __uint_as_float(u & 0xffff0000u);
            a1x = fmaf(w, x0, a1x);
            a1y = fmaf(w, x1, a1y);
            c += w;
        }
    }

    // combine the two per-parity halves: lane sl (+ lane sl+32)
    float ox = __shfl(a1x, sl + 32);
    float oy = __shfl(a1y, sl + 32);
    float oc = __shfl(c,   sl + 32);
    if (h == 0) {
        ((float2*)A1)[(size_t)n * 32 + sl] = make_float2(a1x + ox, a1y + oy);
        if (sl == 0) cnt[n] = c + oc;
    }
}

// 32 rows/block. out = LeakyReLU(A1@W1^T + (A1.*xd)@W2^T + c*(b1+b2)):
// fused as acc += a1*(w1 + xd*w2). Stride-65 LDS transpose (conflict-free).
__global__ __launch_bounds__(256) void node_gemm_kernel(
    const float* __restrict__ A1, const float* __restrict__ cnt,
    const unsigned int* __restrict__ xbf,
    const float* __restrict__ W1, const float* __restrict__ b1,
    const float* __restrict__ W2, const float* __restrict__ b2,
    float* __restrict__ out, int Ntot)
{
    __shared__ float  w1t[64 * 65];
    __shared__ float  w2t[64 * 65];
    __shared__ float4 sA1v[32][16];
    __shared__ float4 sXdv[32][16];
    __shared__ float  scn[32];

    int t = threadIdx.x;
    for (int i = t; i < 64 * 64; i += 256) {
        int o = i >> 6, d = i & 63;
        w1t[d * 65 + o] = W1[i];
        w2t[d * 65 + o] = W2[i];
    }
    int base = blockIdx.x * 32;
    const float4* A1v = (const float4*)A1;
    for (int i = t; i < 32 * 16; i += 256) {
        int r = i >> 4, q = i & 15;
        int row = base + r;
        float4 z; z.x = z.y = z.z = z.w = 0.f;
        if (row < Ntot) {
            sA1v[r][q] = A1v[(size_t)row * 16 + q];
            unsigned int u0 = xbf[row * 32 + 2 * q];
            unsigned int u1 = xbf[row * 32 + 2 * q + 1];
            float4 xd;
            xd.x = __uint_as_float(u0 << 16);
            xd.y = __uint_as_float(u0 & 0xffff0000u);
            xd.z = __uint_as_float(u1 << 16);
            xd.w = __uint_as_float(u1 & 0xffff0000u);
            sXdv[r][q] = xd;
        } else { sA1v[r][q] = z; sXdv[r][q] = z; }
    }
    if (t < 32) scn[t] = (base + t < Ntot) ? cnt[base + t] : 0.f;
    __syncthreads();

    int o  = t & 63;
    int r0 = t >> 6;                  // rows r0 + 4k, k = 0..7
    float bsum = b1[o] + b2[o];
    float acc[8];
    #pragma unroll
    for (int k = 0; k < 8; ++k) acc[k] = scn[r0 + 4 * k] * bsum;

    for (int q = 0; q < 16; ++q) {
        float w10 = w1t[(4 * q + 0) * 65 + o];
        float w11 = w1t[(4 * q + 1) * 65 + o];
        float w12 = w1t[(4 * q + 2) * 65 + o];
        float w13 = w1t[(4 * q + 3) * 65 + o];
        float w20 = w2t[(4 * q + 0) * 65 + o];
        float w21 = w2t[(4 * q + 1) * 65 + o];
        float w22 = w2t[(4 * q + 2) * 65 + o];
        float w23 = w2t[(4 * q + 3) * 65 + o];
        #pragma unroll
        for (int k = 0; k < 8; ++k) {
            float4 a1 = sA1v[r0 + 4 * k][q];
            float4 xd = sXdv[r0 + 4 * k][q];
            acc[k] += a1.x * fmaf(xd.x, w20, w10)
                    + a1.y * fmaf(xd.y, w21, w11)
                    + a1.z * fmaf(xd.z, w22, w12)
                    + a1.w * fmaf(xd.w, w23, w13);
        }
    }

    #pragma unroll
    for (int k = 0; k < 8; ++k) {
        int row = base + r0 + 4 * k;
        if (row < Ntot) {
            float a = acc[k];
            out[(size_t)row * 64 + o] = (a > 0.f) ? a : 0.2f * a;
        }
    }
}

extern "C" void kernel_launch(void* const* d_in, const int* in_sizes, int n_in,
                              void* d_out, int out_size, void* d_ws, size_t ws_size,
                              hipStream_t stream) {
    const float* srcEmb = (const float*)d_in[0];
    const float* dstEmb = (const float*)d_in[1];
    const float* norm   = (const float*)d_in[2];
    const float* W1     = (const float*)d_in[3];
    const float* b1     = (const float*)d_in[4];
    const float* W2     = (const float*)d_in[5];
    const float* b2     = (const float*)d_in[6];
    const int*   es     = (const int*)d_in[7];
    const int*   ed     = (const int*)d_in[8];

    const int n_src = in_sizes[0] / 64;
    const int n_dst = in_sizes[1] / 64;
    const int Ntot  = n_src + n_dst;
    const int E     = in_sizes[7];

    // Workspace carve-up (4-byte units).
    float*        cnt      = (float*)d_ws;                    // Ntot
    int*          offsets  = (int*)(cnt + Ntot);              // Ntot+1
    int*          cursors  = offsets + Ntot + 1;              // Ntot
    int*          partials = cursors + Ntot;                  // 256
    unsigned int* epk      = (unsigned int*)(partials + 256); // E
    unsigned int* xbf      = epk + E;                         // Ntot*32
    float*        A1       = (float*)d_out;                   // Ntot*64

    const int scan_blocks = (Ntot + 1023) / 1024;

    hipMemsetAsync(offsets, 0, (size_t)Ntot * sizeof(int), stream);

    prep_bf16_kernel<<<(Ntot * 32 + 255) / 256, 256, 0, stream>>>(
        srcEmb, dstEmb, xbf, Ntot, n_src);

    hist_kernel<<<(E + 1023) / 1024, 256, 0, stream>>>(ed, offsets, E);

    scan1_kernel<<<scan_blocks, 256, 0, stream>>>(offsets, partials, Ntot);
    scan2_kernel<<<1, 256, 0, stream>>>(partials, scan_blocks);
    add_offsets_kernel<<<(Ntot + 255) / 256, 256, 0, stream>>>(
        offsets, partials, cursors, Ntot, E);

    scatter_kernel<<<(E + 255) / 256, 256, 0, stream>>>(
        es, ed, norm, cursors, epk, E);

    accumulate_kernel<<<(Ntot + 3) / 4, 256, 0, stream>>>(
        xbf, offsets, epk, A1, cnt, Ntot);

    node_gemm_kernel<<<(Ntot + 31) / 32, 256, 0, stream>>>(
        A1, cnt, xbf, W1, b1, W2, b2, (float*)d_out, Ntot);
}